// Round 1
// 1066.079 us; speedup vs baseline: 1.6609x; 1.6609x over previous
//
#include <hip/hip_runtime.h>
#include <stdint.h>

typedef unsigned short u16;
typedef short s16x8 __attribute__((ext_vector_type(8)));
typedef float f32x4 __attribute__((ext_vector_type(4)));

#define HW 65536
#define CD 192
#define C3 576
#define QB ((size_t)HW * C3)

static __device__ __forceinline__ float bf2f(u16 u) {
    return __uint_as_float(((uint32_t)u) << 16);
}
static __device__ __forceinline__ u16 f2bf(float f) {
    uint32_t x = __float_as_uint(f);
    return (u16)((x + 0x7fffu + ((x >> 16) & 1u)) >> 16);  // RNE
}

// ---------------------------------------------------------------------------
// convert fp32 -> bf16 (qkv_w, 576*192 elements)
// ---------------------------------------------------------------------------
__launch_bounds__(256)
__global__ void k_convert(const float* __restrict__ in, u16* __restrict__ out, int n4)
{
    int i = blockIdx.x * 256 + threadIdx.x;
    if (i >= n4) return;
    float4 v = ((const float4*)in)[i];
    ushort4 o;
    o.x = f2bf(v.x); o.y = f2bf(v.y); o.z = f2bf(v.z); o.w = f2bf(v.w);
    ((ushort4*)out)[i] = o;
}

// ---------------------------------------------------------------------------
// K1: QKV gemm (MFMA).  qkvt[p][o] = sum_c qkvw[o][c] * x[b][c][p]
// ---------------------------------------------------------------------------
__launch_bounds__(256, 2)
__global__ void k_qkv(const u16* __restrict__ A, const float* __restrict__ x,
                      u16* __restrict__ O, int b0)
{
    __shared__ __attribute__((aligned(16))) u16 As[192 * 40];
    __shared__ __attribute__((aligned(16))) u16 Xs[128 * 40];
    const int t    = threadIdx.x;
    const int pb   = blockIdx.z;
    const int m0g  = blockIdx.y * 192;
    const int p0   = blockIdx.x * 128;
    const int lane = t & 63, wid = t >> 6;
    const int quad = lane >> 4, l16 = lane & 15;
    const int wm0  = (wid >> 1) * 96, wn0 = (wid & 1) * 64;

    f32x4 acc[6][4];
    #pragma unroll
    for (int i = 0; i < 6; i++)
        #pragma unroll
        for (int j = 0; j < 4; j++) acc[i][j] = f32x4{0.f, 0.f, 0.f, 0.f};

    const float* Xb = x + (size_t)(b0 + pb) * CD * HW;

    for (int kk = 0; kk < 6; kk++) {
        if (kk) __syncthreads();
        #pragma unroll
        for (int i = 0; i < 3; i++) {           // A tile: 192x32
            int s = t + i * 256;
            int m = s >> 2, part = s & 3;
            uint4 v = *(const uint4*)(A + (size_t)(m0g + m) * CD + kk * 32 + part * 8);
            *(uint4*)(&As[m * 40 + part * 8]) = v;
        }
        #pragma unroll
        for (int i = 0; i < 4; i++) {           // X tile: 32 c x 128 p, from fp32
            int s = t + i * 256;
            int c_l = s >> 5, seg = s & 31;
            float4 v = *(const float4*)(Xb + (size_t)(kk * 32 + c_l) * HW + p0 + seg * 4);
            Xs[(seg * 4 + 0) * 40 + c_l] = f2bf(v.x);
            Xs[(seg * 4 + 1) * 40 + c_l] = f2bf(v.y);
            Xs[(seg * 4 + 2) * 40 + c_l] = f2bf(v.z);
            Xs[(seg * 4 + 3) * 40 + c_l] = f2bf(v.w);
        }
        __syncthreads();
        s16x8 af[6], bfr[4];
        #pragma unroll
        for (int i = 0; i < 6; i++)
            af[i] = *(const s16x8*)(&As[(wm0 + i * 16 + l16) * 40 + quad * 8]);
        #pragma unroll
        for (int j = 0; j < 4; j++)
            bfr[j] = *(const s16x8*)(&Xs[(wn0 + j * 16 + l16) * 40 + quad * 8]);
        #pragma unroll
        for (int i = 0; i < 6; i++)
            #pragma unroll
            for (int j = 0; j < 4; j++)
                acc[i][j] = __builtin_amdgcn_mfma_f32_16x16x32_bf16(af[i], bfr[j], acc[i][j], 0, 0, 0);
    }

    u16* Ob = O + QB * pb;
    #pragma unroll
    for (int i = 0; i < 6; i++) {
        const int o = m0g + wm0 + i * 16 + quad * 4;   // rows o..o+3
        #pragma unroll
        for (int j = 0; j < 4; j++) {
            const int p = p0 + wn0 + j * 16 + l16;
            ushort4 v;
            v.x = f2bf(acc[i][j][0]); v.y = f2bf(acc[i][j][1]);
            v.z = f2bf(acc[i][j][2]); v.w = f2bf(acc[i][j][3]);
            *(ushort4*)(Ob + (size_t)p * C3 + o) = v;
        }
    }
}

// ---------------------------------------------------------------------------
// K2: depthwise 3x3, SAME padding, staged: block = (8-wide w chunk, h, pb).
// ---------------------------------------------------------------------------
__launch_bounds__(256)
__global__ void k_dw(const u16* __restrict__ qkv, const float* __restrict__ dww,
                     u16* __restrict__ out)
{
    __shared__ __attribute__((aligned(16))) u16 stage[3 * 10 * 576];
    __shared__ float wts[5184];
    const int t  = threadIdx.x;
    const int pb = blockIdx.z;
    const int h  = blockIdx.y;
    const int w0 = blockIdx.x * 8;

    for (int i = t; i < 5184; i += 256) wts[i] = dww[i];
    const u16* src = qkv + (size_t)pb * QB;
    #pragma unroll
    for (int i = 0; i < 9; i++) {
        int s = t + i * 256;
        if (s < 2160) {
            int c0 = (s % 72) * 8;
            int r = s / 72;
            int wpos = r % 10, hh = r / 10;
            int gh = h + hh - 1, gw = w0 + wpos - 1;
            uint4 v = make_uint4(0, 0, 0, 0);
            if ((unsigned)gh < 256u && (unsigned)gw < 256u)
                v = *(const uint4*)(src + ((size_t)gh * 256 + gw) * C3 + c0);
            *(uint4*)(&stage[(hh * 10 + wpos) * 576 + c0]) = v;
        }
    }
    __syncthreads();

    u16* dst = out + (size_t)pb * QB + ((size_t)h * 256 + w0) * C3;
    for (int ci = 0; ci < 3; ci++) {
        int c = t + ci * 256;
        if (c >= C3) break;
        float w9[9];
        #pragma unroll
        for (int k = 0; k < 9; k++) w9[k] = wts[c * 9 + k];
        float acc8[8] = {0.f, 0.f, 0.f, 0.f, 0.f, 0.f, 0.f, 0.f};
        #pragma unroll
        for (int hh = 0; hh < 3; hh++) {
            float s10[10];
            #pragma unroll
            for (int wp = 0; wp < 10; wp++) s10[wp] = bf2f(stage[(hh * 10 + wp) * 576 + c]);
            #pragma unroll
            for (int wi = 0; wi < 8; wi++)
                acc8[wi] += s10[wi]     * w9[hh * 3]
                          + s10[wi + 1] * w9[hh * 3 + 1]
                          + s10[wi + 2] * w9[hh * 3 + 2];
        }
        #pragma unroll
        for (int wi = 0; wi < 8; wi++) dst[(size_t)wi * C3 + c] = f2bf(acc8[wi]);
    }
}

// ---------------------------------------------------------------------------
// K3 (new): per-(b,h) 48x48 Gram matrix G = [q;k]·[q;k]^T summed over pixels.
//   Replaces k_sumsq (diag of G) + k_attn (q·k block of G) with MFMA.
//   a-frag layout == b-frag layout for 16x16x32, so mfma(f_i, f_j) = S_i·S_j^T.
//   Grid: (GNB pixel-slices, 8 heads, P batches); each block does HW/GNB pixels
//   in NCHUNK chunks of 256, double-buffered LDS, acc held in registers,
//   one cross-wave LDS reduce + one atomic phase at the end.
// ---------------------------------------------------------------------------
#define GNB    16
#define NCHUNK 16   /* (HW/GNB)/256 */

__launch_bounds__(256, 2)
__global__ void k_gram(const u16* __restrict__ dwt, float* __restrict__ gram, int b0)
{
    __shared__ __attribute__((aligned(16))) u16 S[2][48 * 264];
    const int t    = threadIdx.x;
    const int pb   = blockIdx.z, hh = blockIdx.y, blk = blockIdx.x;
    const int lane = t & 63, wid = t >> 6;
    const int quad = lane >> 4, l16 = lane & 15;
    const u16* src = dwt + (size_t)pb * QB + (size_t)blk * (HW / GNB) * C3;
    const int qcol = hh * 24, kcol = CD + hh * 24;
    // staging role: pixel pair n0,n0+1 ; parts {0,2,4} (t<128) or {1,3,5} (t>=128)
    const int sp_n0 = (t & 127) * 2;
    const int sp_ph = t >> 7;

    f32x4 acc[6];
    #pragma unroll
    for (int i = 0; i < 6; i++) acc[i] = f32x4{0.f, 0.f, 0.f, 0.f};

    uint4 r0[3], r1[3];

    auto stage_load = [&](int cc) {
        const u16* sp = src + (size_t)(cc * 256 + sp_n0) * C3;
        #pragma unroll
        for (int i = 0; i < 3; i++) {
            int part = i * 2 + sp_ph;
            int col  = part < 3 ? qcol + part * 8 : kcol + (part - 3) * 8;
            r0[i] = *(const uint4*)(sp + col);
            r1[i] = *(const uint4*)(sp + C3 + col);
        }
    };
    auto stage_write = [&](int bb) {
        #pragma unroll
        for (int i = 0; i < 3; i++) {
            int part = i * 2 + sp_ph;
            int dstc = part < 3 ? part * 8 : 24 + (part - 3) * 8;
            const u16* a = (const u16*)&r0[i];
            const u16* b = (const u16*)&r1[i];
            #pragma unroll
            for (int w = 0; w < 8; w++) {
                uint32_t d = (uint32_t)a[w] | ((uint32_t)b[w] << 16);
                *(uint32_t*)&S[bb][(dstc + w) * 264 + sp_n0] = d;  // [ch][pix] transpose
            }
        }
    };

    stage_load(0);
    stage_write(0);
    for (int c = 0; c < NCHUNK; c++) {
        const int bb = c & 1;
        __syncthreads();
        if (c + 1 < NCHUNK) stage_load(c + 1);       // issue early: hide HBM latency
        #pragma unroll
        for (int kk = 0; kk < 2; kk++) {              // wave owns 2 of 8 k-steps
            const int k0 = (wid + kk * 4) * 32 + quad * 8;
            s16x8 f0 = *(const s16x8*)&S[bb][( 0 + l16) * 264 + k0];
            s16x8 f1 = *(const s16x8*)&S[bb][(16 + l16) * 264 + k0];
            s16x8 f2 = *(const s16x8*)&S[bb][(32 + l16) * 264 + k0];
            acc[0] = __builtin_amdgcn_mfma_f32_16x16x32_bf16(f0, f0, acc[0], 0, 0, 0);
            acc[1] = __builtin_amdgcn_mfma_f32_16x16x32_bf16(f0, f1, acc[1], 0, 0, 0);
            acc[2] = __builtin_amdgcn_mfma_f32_16x16x32_bf16(f0, f2, acc[2], 0, 0, 0);
            acc[3] = __builtin_amdgcn_mfma_f32_16x16x32_bf16(f1, f1, acc[3], 0, 0, 0);
            acc[4] = __builtin_amdgcn_mfma_f32_16x16x32_bf16(f1, f2, acc[4], 0, 0, 0);
            acc[5] = __builtin_amdgcn_mfma_f32_16x16x32_bf16(f2, f2, acc[5], 0, 0, 0);
        }
        if (c + 1 < NCHUNK) stage_write(bb ^ 1);      // write-late into other buffer
    }

    // cross-wave reduce in LDS (reuse staging buffers), then one atomic phase
    __syncthreads();
    float* red = (float*)&S[0][0];                    // 4*6*256 floats = 24 KB
    #pragma unroll
    for (int tt = 0; tt < 6; tt++)
        #pragma unroll
        for (int r = 0; r < 4; r++)
            red[(wid * 6 + tt) * 256 + (quad * 4 + r) * 16 + l16] = acc[tt][r];
    __syncthreads();
    const int TIr[6] = {0, 0, 0, 1, 1, 2};
    const int TJr[6] = {0, 1, 2, 1, 2, 2};
    float* gb = gram + ((size_t)(b0 + pb) * 8 + hh) * 2304;
    #pragma unroll
    for (int k = 0; k < 6; k++) {
        float s = red[(0 * 6 + k) * 256 + t] + red[(1 * 6 + k) * 256 + t]
                + red[(2 * 6 + k) * 256 + t] + red[(3 * 6 + k) * 256 + t];
        int row = TIr[k] * 16 + (t >> 4);
        int col = TJr[k] * 16 + (t & 15);
        atomicAdd(&gb[row * 48 + col], s);
    }
}

// ---------------------------------------------------------------------------
// K4b: norm scales from Gram diag + temperature, softmax over e.
// ---------------------------------------------------------------------------
__global__ void k_softmax(const float* __restrict__ gram, const float* __restrict__ temp,
                          float* __restrict__ attnS, int b0)
{
    const int b = b0 + blockIdx.y, hh = blockIdx.x, t = threadIdx.x;
    const float* G = gram + ((size_t)b * 8 + hh) * 2304;
    __shared__ float ksc[24];
    if (t < 24) ksc[t] = 1.f / fmaxf(sqrtf(G[(24 + t) * 48 + 24 + t]), 1e-12f);
    __syncthreads();
    if (t < 24) {
        const float tp = temp[hh];
        const float qs = 1.f / fmaxf(sqrtf(G[t * 48 + t]), 1e-12f);
        const float* row = G + t * 48 + 24;           // q-row d, k-cols 24..47
        float v[24], m = -1e30f;
        #pragma unroll
        for (int e = 0; e < 24; e++) { v[e] = row[e] * qs * ksc[e] * tp; m = fmaxf(m, v[e]); }
        float ssum = 0.f;
        #pragma unroll
        for (int e = 0; e < 24; e++) { v[e] = expf(v[e] - m); ssum += v[e]; }
        const float inv = 1.f / ssum;
        float* orow = attnS + ((size_t)b * 8 + hh) * 576 + t * 24;
        #pragma unroll
        for (int e = 0; e < 24; e++) orow[e] = v[e] * inv;
    }
}

// ---------------------------------------------------------------------------
// K4c: Meff[b][o][h*24+e] = sum_d proj_w[o][h*24+d] * attnS[b][h][d][e]
// ---------------------------------------------------------------------------
__launch_bounds__(256)
__global__ void k_meff(const float* __restrict__ attnS, const float* __restrict__ projw,
                       u16* __restrict__ meff, int b0, int total)
{
    int g = blockIdx.x * 256 + threadIdx.x;
    if (g >= total) return;
    int b_l = g / 36864, rem = g % 36864;
    int o = rem / CD, c = rem % CD;
    int hh = c / 24, e = c % 24;
    int b = b0 + b_l;
    const float* Arow = attnS + ((size_t)b * 8 + hh) * 576;
    const float* Prow = projw + o * CD + hh * 24;
    float acc = 0.f;
    #pragma unroll
    for (int d = 0; d < 24; d++) acc += Prow[d] * Arow[d * 24 + e];
    meff[(size_t)b * 36864 + o * CD + c] = f2bf(acc);
}

// ---------------------------------------------------------------------------
// K5: out[b][o][p] = sum_c meff[b][o][c] * dwt[p][384+c]   (MFMA, fp32 out)
// ---------------------------------------------------------------------------
__launch_bounds__(256, 2)
__global__ void k_gemm2(const u16* __restrict__ A, const u16* __restrict__ X,
                        float* __restrict__ O)
{
    __shared__ __attribute__((aligned(16))) u16 As[192 * 40];
    __shared__ __attribute__((aligned(16))) u16 Xs[128 * 40];
    const int t    = threadIdx.x;
    const int pb   = blockIdx.z;
    const int p0   = blockIdx.x * 128;
    const int lane = t & 63, wid = t >> 6;
    const int quad = lane >> 4, l16 = lane & 15;
    const int wm0  = (wid >> 1) * 96, wn0 = (wid & 1) * 64;

    f32x4 acc[6][4];
    #pragma unroll
    for (int i = 0; i < 6; i++)
        #pragma unroll
        for (int j = 0; j < 4; j++) acc[i][j] = f32x4{0.f, 0.f, 0.f, 0.f};

    const u16* Ab = A + (size_t)36864 * pb;
    const u16* Xb = X + QB * pb;

    for (int kk = 0; kk < 6; kk++) {
        if (kk) __syncthreads();
        #pragma unroll
        for (int i = 0; i < 3; i++) {           // A tile: 192x32
            int s = t + i * 256;
            int m = s >> 2, part = s & 3;
            uint4 v = *(const uint4*)(Ab + (size_t)m * CD + kk * 32 + part * 8);
            *(uint4*)(&As[m * 40 + part * 8]) = v;
        }
        #pragma unroll
        for (int i = 0; i < 2; i++) {           // X tile: 128 p x 32 c (v cols)
            int s = t + i * 256;
            int p = s >> 2, part = s & 3;
            uint4 v = *(const uint4*)(Xb + (size_t)(p0 + p) * C3 + 384 + kk * 32 + part * 8);
            *(uint4*)(&Xs[p * 40 + part * 8]) = v;
        }
        __syncthreads();
        s16x8 af[6], bfr[4];
        #pragma unroll
        for (int i = 0; i < 6; i++)
            af[i] = *(const s16x8*)(&As[(wm0 + i * 16 + l16) * 40 + quad * 8]);
        #pragma unroll
        for (int j = 0; j < 4; j++)
            bfr[j] = *(const s16x8*)(&Xs[(wn0 + j * 16 + l16) * 40 + quad * 8]);
        #pragma unroll
        for (int i = 0; i < 6; i++)
            #pragma unroll
            for (int j = 0; j < 4; j++)
                acc[i][j] = __builtin_amdgcn_mfma_f32_16x16x32_bf16(af[i], bfr[j], acc[i][j], 0, 0, 0);
    }

    float* Ob = O + (size_t)CD * HW * pb;
    #pragma unroll
    for (int i = 0; i < 6; i++) {
        const int o = wm0 + i * 16 + quad * 4;
        #pragma unroll
        for (int j = 0; j < 4; j++) {
            const int p = p0 + wn0 + j * 16 + l16;
            #pragma unroll
            for (int r = 0; r < 4; r++)
                Ob[(size_t)(o + r) * HW + p] = acc[i][j][r];
        }
    }
}

// ---------------------------------------------------------------------------
extern "C" void kernel_launch(void* const* d_in, const int* in_sizes, int n_in,
                              void* d_out, int out_size, void* d_ws, size_t ws_size,
                              hipStream_t stream)
{
    (void)out_size;
    const float* x     = (const float*)d_in[0];
    const float* qkvw  = (const float*)d_in[1];
    const float* dww   = (const float*)d_in[2];
    const float* projw = (const float*)d_in[3];
    const float* temp  = (const float*)d_in[4];
    for (int i = 0; i < n_in; i++) {
        switch (in_sizes[i]) {
            case 50331648: x     = (const float*)d_in[i]; break;
            case 110592:   qkvw  = (const float*)d_in[i]; break;
            case 5184:     dww   = (const float*)d_in[i]; break;
            case 36864:    projw = (const float*)d_in[i]; break;
            case 8:        temp  = (const float*)d_in[i]; break;
            default: break;
        }
    }
    float* out = (float*)d_out;          // reference output dtype = float32
    char* ws = (char*)d_ws;

    const size_t gram_off  = 0;                      // 4*8*48*48*4 = 294912 B
    const size_t asmx_off  = gram_off + 294912;      // 4*8*576*4   = 73728 B
    const size_t meff_off  = asmx_off + 73728;       // 4*36864*2   = 294912 B
    const size_t qkvwb_off = meff_off + 294912;      // 576*192*2   = 221184 B
    const size_t big_off   = (qkvwb_off + 221184 + 255) & ~(size_t)255;

    int P = 4;   // batches per pass; shrink if workspace is small
    while (P > 1 && big_off + (size_t)P * 2 * QB * 2 > ws_size) P >>= 1;

    float* gram  = (float*)(ws + gram_off);
    float* attnS = (float*)(ws + asmx_off);
    u16*   meff  = (u16*)(ws + meff_off);
    u16*   qkvwb = (u16*)(ws + qkvwb_off);
    u16*   qkvt  = (u16*)(ws + big_off);
    u16*   dwt   = qkvt + (size_t)P * QB;

    hipMemsetAsync(ws + gram_off, 0, 294912, stream);  // zero gram accumulators
    k_convert<<<dim3(108), 256, 0, stream>>>(qkvw, qkvwb, 110592 / 4);

    for (int b0 = 0; b0 < 4; b0 += P) {
        k_qkv<<<dim3(512, 3, P), 256, 0, stream>>>(qkvwb, x, qkvt, b0);
        k_dw<<<dim3(32, 256, P), 256, 0, stream>>>(qkvt, dww, dwt);
        k_gram<<<dim3(GNB, 8, P), 256, 0, stream>>>(dwt, gram, b0);
        k_softmax<<<dim3(8, P), 64, 0, stream>>>(gram, temp, attnS, b0);
        k_meff<<<dim3(P * 144), 256, 0, stream>>>(attnS, projw, meff, b0, P * 36864);
        k_gemm2<<<dim3(512, 1, P), 256, 0, stream>>>(
            meff + (size_t)b0 * 36864, dwt, out + (size_t)b0 * CD * HW);
    }
}

// Round 2
// 921.385 us; speedup vs baseline: 1.9218x; 1.1570x over previous
//
#include <hip/hip_runtime.h>
#include <stdint.h>

typedef unsigned short u16;
typedef short s16x8 __attribute__((ext_vector_type(8)));
typedef float f32x4 __attribute__((ext_vector_type(4)));

#define HW 65536
#define CD 192
#define C3 576
#define QB ((size_t)HW * C3)

static __device__ __forceinline__ float bf2f(u16 u) {
    return __uint_as_float(((uint32_t)u) << 16);
}
static __device__ __forceinline__ u16 f2bf(float f) {
    uint32_t x = __float_as_uint(f);
    return (u16)((x + 0x7fffu + ((x >> 16) & 1u)) >> 16);  // RNE
}

// ---------------------------------------------------------------------------
// convert fp32 -> bf16 (qkv_w, 576*192 elements)
// ---------------------------------------------------------------------------
__launch_bounds__(256)
__global__ void k_convert(const float* __restrict__ in, u16* __restrict__ out, int n4)
{
    int i = blockIdx.x * 256 + threadIdx.x;
    if (i >= n4) return;
    float4 v = ((const float4*)in)[i];
    ushort4 o;
    o.x = f2bf(v.x); o.y = f2bf(v.y); o.z = f2bf(v.z); o.w = f2bf(v.w);
    ((ushort4*)out)[i] = o;
}

// ---------------------------------------------------------------------------
// K1: QKV gemm (MFMA).  qkvt[p][o] = sum_c qkvw[o][c] * x[b][c][p]
// ---------------------------------------------------------------------------
__launch_bounds__(256, 2)
__global__ void k_qkv(const u16* __restrict__ A, const float* __restrict__ x,
                      u16* __restrict__ O, int b0)
{
    __shared__ __attribute__((aligned(16))) u16 As[192 * 40];
    __shared__ __attribute__((aligned(16))) u16 Xs[128 * 40];
    const int t    = threadIdx.x;
    const int pb   = blockIdx.z;
    const int m0g  = blockIdx.y * 192;
    const int p0   = blockIdx.x * 128;
    const int lane = t & 63, wid = t >> 6;
    const int quad = lane >> 4, l16 = lane & 15;
    const int wm0  = (wid >> 1) * 96, wn0 = (wid & 1) * 64;

    f32x4 acc[6][4];
    #pragma unroll
    for (int i = 0; i < 6; i++)
        #pragma unroll
        for (int j = 0; j < 4; j++) acc[i][j] = f32x4{0.f, 0.f, 0.f, 0.f};

    const float* Xb = x + (size_t)(b0 + pb) * CD * HW;

    for (int kk = 0; kk < 6; kk++) {
        if (kk) __syncthreads();
        #pragma unroll
        for (int i = 0; i < 3; i++) {           // A tile: 192x32
            int s = t + i * 256;
            int m = s >> 2, part = s & 3;
            uint4 v = *(const uint4*)(A + (size_t)(m0g + m) * CD + kk * 32 + part * 8);
            *(uint4*)(&As[m * 40 + part * 8]) = v;
        }
        #pragma unroll
        for (int i = 0; i < 4; i++) {           // X tile: 32 c x 128 p, from fp32
            int s = t + i * 256;
            int c_l = s >> 5, seg = s & 31;
            float4 v = *(const float4*)(Xb + (size_t)(kk * 32 + c_l) * HW + p0 + seg * 4);
            Xs[(seg * 4 + 0) * 40 + c_l] = f2bf(v.x);
            Xs[(seg * 4 + 1) * 40 + c_l] = f2bf(v.y);
            Xs[(seg * 4 + 2) * 40 + c_l] = f2bf(v.z);
            Xs[(seg * 4 + 3) * 40 + c_l] = f2bf(v.w);
        }
        __syncthreads();
        s16x8 af[6], bfr[4];
        #pragma unroll
        for (int i = 0; i < 6; i++)
            af[i] = *(const s16x8*)(&As[(wm0 + i * 16 + l16) * 40 + quad * 8]);
        #pragma unroll
        for (int j = 0; j < 4; j++)
            bfr[j] = *(const s16x8*)(&Xs[(wn0 + j * 16 + l16) * 40 + quad * 8]);
        #pragma unroll
        for (int i = 0; i < 6; i++)
            #pragma unroll
            for (int j = 0; j < 4; j++)
                acc[i][j] = __builtin_amdgcn_mfma_f32_16x16x32_bf16(af[i], bfr[j], acc[i][j], 0, 0, 0);
    }

    u16* Ob = O + QB * pb;
    #pragma unroll
    for (int i = 0; i < 6; i++) {
        const int o = m0g + wm0 + i * 16 + quad * 4;   // rows o..o+3
        #pragma unroll
        for (int j = 0; j < 4; j++) {
            const int p = p0 + wn0 + j * 16 + l16;
            ushort4 v;
            v.x = f2bf(acc[i][j][0]); v.y = f2bf(acc[i][j][1]);
            v.z = f2bf(acc[i][j][2]); v.w = f2bf(acc[i][j][3]);
            *(ushort4*)(Ob + (size_t)p * C3 + o) = v;
        }
    }
}

// ---------------------------------------------------------------------------
// K2 (v2): depthwise 3x3, SAME padding — no pixel staging.
//   Block = 576 threads: 72 channel-groups (8ch each) x 8 pixel-slots.
//   Thread: fixed cg, 4 consecutive output pixels, sliding 6-wide window,
//   weights (72 floats) in registers via pad-73 LDS transpose (conflict-free).
//   Neighbor taps read straight from L1/L2 (layout [p][c] -> waves read
//   contiguous 1KB lines).
// ---------------------------------------------------------------------------
__launch_bounds__(576)
__global__ void k_dw(const u16* __restrict__ qkv, const float* __restrict__ dww,
                     u16* __restrict__ out)
{
    __shared__ float wlds[72 * 73];
    const int t  = threadIdx.x;
    const int pb = blockIdx.z;
    const int h  = blockIdx.y;
    const int w0 = blockIdx.x * 32;

    for (int i = t; i < 5184; i += 576)
        wlds[(i / 72) * 73 + (i % 72)] = dww[i];

    const int cg    = t % 72;          // channels cg*8 .. cg*8+7
    const int ps    = t / 72;          // pixel slot 0..7
    const int wbase = w0 + ps * 4;     // output pixels wbase..wbase+3
    __syncthreads();

    float wr[72];                      // wr[ch*9 + (dh*3+dw)]
    #pragma unroll
    for (int k = 0; k < 72; k++) wr[k] = wlds[cg * 73 + k];

    const u16* src = qkv + (size_t)pb * QB + (size_t)cg * 8;
    float acc[4][8];
    #pragma unroll
    for (int i = 0; i < 4; i++)
        #pragma unroll
        for (int j = 0; j < 8; j++) acc[i][j] = 0.f;

    #pragma unroll
    for (int dh = 0; dh < 3; dh++) {
        int gh = h + dh - 1;
        if ((unsigned)gh < 256u) {
            const u16* rsrc = src + (size_t)gh * 256 * C3;
            float v[6][8];
            #pragma unroll
            for (int c = 0; c < 6; c++) {
                int gw = wbase + c - 1;
                uint4 raw = make_uint4(0u, 0u, 0u, 0u);
                if ((unsigned)gw < 256u)
                    raw = *(const uint4*)(rsrc + (size_t)gw * C3);
                const u16* rp = (const u16*)&raw;
                #pragma unroll
                for (int j = 0; j < 8; j++) v[c][j] = bf2f(rp[j]);
            }
            #pragma unroll
            for (int wi = 0; wi < 4; wi++)
                #pragma unroll
                for (int dw = 0; dw < 3; dw++)
                    #pragma unroll
                    for (int j = 0; j < 8; j++)
                        acc[wi][j] += v[wi + dw][j] * wr[j * 9 + dh * 3 + dw];
        }
    }

    u16* dst = out + (size_t)pb * QB + ((size_t)h * 256 + wbase) * C3 + cg * 8;
    #pragma unroll
    for (int wi = 0; wi < 4; wi++) {
        uint4 o;
        o.x = (uint32_t)f2bf(acc[wi][0]) | ((uint32_t)f2bf(acc[wi][1]) << 16);
        o.y = (uint32_t)f2bf(acc[wi][2]) | ((uint32_t)f2bf(acc[wi][3]) << 16);
        o.z = (uint32_t)f2bf(acc[wi][4]) | ((uint32_t)f2bf(acc[wi][5]) << 16);
        o.w = (uint32_t)f2bf(acc[wi][6]) | ((uint32_t)f2bf(acc[wi][7]) << 16);
        *(uint4*)(dst + (size_t)wi * C3) = o;
    }
}

// ---------------------------------------------------------------------------
// K3: per-(b,h) 48x48 Gram matrix G = [q;k]·[q;k]^T summed over pixels (MFMA).
// ---------------------------------------------------------------------------
#define GNB    16
#define NCHUNK 16   /* (HW/GNB)/256 */

__launch_bounds__(256, 2)
__global__ void k_gram(const u16* __restrict__ dwt, float* __restrict__ gram, int b0)
{
    __shared__ __attribute__((aligned(16))) u16 S[2][48 * 264];
    const int t    = threadIdx.x;
    const int pb   = blockIdx.z, hh = blockIdx.y, blk = blockIdx.x;
    const int lane = t & 63, wid = t >> 6;
    const int quad = lane >> 4, l16 = lane & 15;
    const u16* src = dwt + (size_t)pb * QB + (size_t)blk * (HW / GNB) * C3;
    const int qcol = hh * 24, kcol = CD + hh * 24;
    const int sp_n0 = (t & 127) * 2;
    const int sp_ph = t >> 7;

    f32x4 acc[6];
    #pragma unroll
    for (int i = 0; i < 6; i++) acc[i] = f32x4{0.f, 0.f, 0.f, 0.f};

    uint4 r0[3], r1[3];

    auto stage_load = [&](int cc) {
        const u16* sp = src + (size_t)(cc * 256 + sp_n0) * C3;
        #pragma unroll
        for (int i = 0; i < 3; i++) {
            int part = i * 2 + sp_ph;
            int col  = part < 3 ? qcol + part * 8 : kcol + (part - 3) * 8;
            r0[i] = *(const uint4*)(sp + col);
            r1[i] = *(const uint4*)(sp + C3 + col);
        }
    };
    auto stage_write = [&](int bb) {
        #pragma unroll
        for (int i = 0; i < 3; i++) {
            int part = i * 2 + sp_ph;
            int dstc = part < 3 ? part * 8 : 24 + (part - 3) * 8;
            const u16* a = (const u16*)&r0[i];
            const u16* b = (const u16*)&r1[i];
            #pragma unroll
            for (int w = 0; w < 8; w++) {
                uint32_t d = (uint32_t)a[w] | ((uint32_t)b[w] << 16);
                *(uint32_t*)&S[bb][(dstc + w) * 264 + sp_n0] = d;
            }
        }
    };

    stage_load(0);
    stage_write(0);
    for (int c = 0; c < NCHUNK; c++) {
        const int bb = c & 1;
        __syncthreads();
        if (c + 1 < NCHUNK) stage_load(c + 1);
        #pragma unroll
        for (int kk = 0; kk < 2; kk++) {
            const int k0 = (wid + kk * 4) * 32 + quad * 8;
            s16x8 f0 = *(const s16x8*)&S[bb][( 0 + l16) * 264 + k0];
            s16x8 f1 = *(const s16x8*)&S[bb][(16 + l16) * 264 + k0];
            s16x8 f2 = *(const s16x8*)&S[bb][(32 + l16) * 264 + k0];
            acc[0] = __builtin_amdgcn_mfma_f32_16x16x32_bf16(f0, f0, acc[0], 0, 0, 0);
            acc[1] = __builtin_amdgcn_mfma_f32_16x16x32_bf16(f0, f1, acc[1], 0, 0, 0);
            acc[2] = __builtin_amdgcn_mfma_f32_16x16x32_bf16(f0, f2, acc[2], 0, 0, 0);
            acc[3] = __builtin_amdgcn_mfma_f32_16x16x32_bf16(f1, f1, acc[3], 0, 0, 0);
            acc[4] = __builtin_amdgcn_mfma_f32_16x16x32_bf16(f1, f2, acc[4], 0, 0, 0);
            acc[5] = __builtin_amdgcn_mfma_f32_16x16x32_bf16(f2, f2, acc[5], 0, 0, 0);
        }
        if (c + 1 < NCHUNK) stage_write(bb ^ 1);
    }

    __syncthreads();
    float* red = (float*)&S[0][0];
    #pragma unroll
    for (int tt = 0; tt < 6; tt++)
        #pragma unroll
        for (int r = 0; r < 4; r++)
            red[(wid * 6 + tt) * 256 + (quad * 4 + r) * 16 + l16] = acc[tt][r];
    __syncthreads();
    const int TIr[6] = {0, 0, 0, 1, 1, 2};
    const int TJr[6] = {0, 1, 2, 1, 2, 2};
    float* gb = gram + ((size_t)(b0 + pb) * 8 + hh) * 2304;
    #pragma unroll
    for (int k = 0; k < 6; k++) {
        float s = red[(0 * 6 + k) * 256 + t] + red[(1 * 6 + k) * 256 + t]
                + red[(2 * 6 + k) * 256 + t] + red[(3 * 6 + k) * 256 + t];
        int row = TIr[k] * 16 + (t >> 4);
        int col = TJr[k] * 16 + (t & 15);
        atomicAdd(&gb[row * 48 + col], s);
    }
}

// ---------------------------------------------------------------------------
// K4b: norm scales from Gram diag + temperature, softmax over e.
// ---------------------------------------------------------------------------
__global__ void k_softmax(const float* __restrict__ gram, const float* __restrict__ temp,
                          float* __restrict__ attnS, int b0)
{
    const int b = b0 + blockIdx.y, hh = blockIdx.x, t = threadIdx.x;
    const float* G = gram + ((size_t)b * 8 + hh) * 2304;
    __shared__ float ksc[24];
    if (t < 24) ksc[t] = 1.f / fmaxf(sqrtf(G[(24 + t) * 48 + 24 + t]), 1e-12f);
    __syncthreads();
    if (t < 24) {
        const float tp = temp[hh];
        const float qs = 1.f / fmaxf(sqrtf(G[t * 48 + t]), 1e-12f);
        const float* row = G + t * 48 + 24;
        float v[24], m = -1e30f;
        #pragma unroll
        for (int e = 0; e < 24; e++) { v[e] = row[e] * qs * ksc[e] * tp; m = fmaxf(m, v[e]); }
        float ssum = 0.f;
        #pragma unroll
        for (int e = 0; e < 24; e++) { v[e] = expf(v[e] - m); ssum += v[e]; }
        const float inv = 1.f / ssum;
        float* orow = attnS + ((size_t)b * 8 + hh) * 576 + t * 24;
        #pragma unroll
        for (int e = 0; e < 24; e++) orow[e] = v[e] * inv;
    }
}

// ---------------------------------------------------------------------------
// K4c: Meff[b][o][h*24+e] = sum_d proj_w[o][h*24+d] * attnS[b][h][d][e]
// ---------------------------------------------------------------------------
__launch_bounds__(256)
__global__ void k_meff(const float* __restrict__ attnS, const float* __restrict__ projw,
                       u16* __restrict__ meff, int b0, int total)
{
    int g = blockIdx.x * 256 + threadIdx.x;
    if (g >= total) return;
    int b_l = g / 36864, rem = g % 36864;
    int o = rem / CD, c = rem % CD;
    int hh = c / 24, e = c % 24;
    int b = b0 + b_l;
    const float* Arow = attnS + ((size_t)b * 8 + hh) * 576;
    const float* Prow = projw + o * CD + hh * 24;
    float acc = 0.f;
    #pragma unroll
    for (int d = 0; d < 24; d++) acc += Prow[d] * Arow[d * 24 + e];
    meff[(size_t)b * 36864 + o * CD + c] = f2bf(acc);
}

// ---------------------------------------------------------------------------
// K5: out[b][o][p] = sum_c meff[b][o][c] * dwt[p][384+c]   (MFMA, fp32 out)
// ---------------------------------------------------------------------------
__launch_bounds__(256, 2)
__global__ void k_gemm2(const u16* __restrict__ A, const u16* __restrict__ X,
                        float* __restrict__ O)
{
    __shared__ __attribute__((aligned(16))) u16 As[192 * 40];
    __shared__ __attribute__((aligned(16))) u16 Xs[128 * 40];
    const int t    = threadIdx.x;
    const int pb   = blockIdx.z;
    const int p0   = blockIdx.x * 128;
    const int lane = t & 63, wid = t >> 6;
    const int quad = lane >> 4, l16 = lane & 15;
    const int wm0  = (wid >> 1) * 96, wn0 = (wid & 1) * 64;

    f32x4 acc[6][4];
    #pragma unroll
    for (int i = 0; i < 6; i++)
        #pragma unroll
        for (int j = 0; j < 4; j++) acc[i][j] = f32x4{0.f, 0.f, 0.f, 0.f};

    const u16* Ab = A + (size_t)36864 * pb;
    const u16* Xb = X + QB * pb;

    for (int kk = 0; kk < 6; kk++) {
        if (kk) __syncthreads();
        #pragma unroll
        for (int i = 0; i < 3; i++) {           // A tile: 192x32
            int s = t + i * 256;
            int m = s >> 2, part = s & 3;
            uint4 v = *(const uint4*)(Ab + (size_t)m * CD + kk * 32 + part * 8);
            *(uint4*)(&As[m * 40 + part * 8]) = v;
        }
        #pragma unroll
        for (int i = 0; i < 2; i++) {           // X tile: 128 p x 32 c (v cols)
            int s = t + i * 256;
            int p = s >> 2, part = s & 3;
            uint4 v = *(const uint4*)(Xb + (size_t)(p0 + p) * C3 + 384 + kk * 32 + part * 8);
            *(uint4*)(&Xs[p * 40 + part * 8]) = v;
        }
        __syncthreads();
        s16x8 af[6], bfr[4];
        #pragma unroll
        for (int i = 0; i < 6; i++)
            af[i] = *(const s16x8*)(&As[(wm0 + i * 16 + l16) * 40 + quad * 8]);
        #pragma unroll
        for (int j = 0; j < 4; j++)
            bfr[j] = *(const s16x8*)(&Xs[(wn0 + j * 16 + l16) * 40 + quad * 8]);
        #pragma unroll
        for (int i = 0; i < 6; i++)
            #pragma unroll
            for (int j = 0; j < 4; j++)
                acc[i][j] = __builtin_amdgcn_mfma_f32_16x16x32_bf16(af[i], bfr[j], acc[i][j], 0, 0, 0);
    }

    float* Ob = O + (size_t)CD * HW * pb;
    #pragma unroll
    for (int i = 0; i < 6; i++) {
        const int o = wm0 + i * 16 + quad * 4;
        #pragma unroll
        for (int j = 0; j < 4; j++) {
            const int p = p0 + wn0 + j * 16 + l16;
            #pragma unroll
            for (int r = 0; r < 4; r++)
                Ob[(size_t)(o + r) * HW + p] = acc[i][j][r];
        }
    }
}

// ---------------------------------------------------------------------------
extern "C" void kernel_launch(void* const* d_in, const int* in_sizes, int n_in,
                              void* d_out, int out_size, void* d_ws, size_t ws_size,
                              hipStream_t stream)
{
    (void)out_size;
    const float* x     = (const float*)d_in[0];
    const float* qkvw  = (const float*)d_in[1];
    const float* dww   = (const float*)d_in[2];
    const float* projw = (const float*)d_in[3];
    const float* temp  = (const float*)d_in[4];
    for (int i = 0; i < n_in; i++) {
        switch (in_sizes[i]) {
            case 50331648: x     = (const float*)d_in[i]; break;
            case 110592:   qkvw  = (const float*)d_in[i]; break;
            case 5184:     dww   = (const float*)d_in[i]; break;
            case 36864:    projw = (const float*)d_in[i]; break;
            case 8:        temp  = (const float*)d_in[i]; break;
            default: break;
        }
    }
    float* out = (float*)d_out;          // reference output dtype = float32
    char* ws = (char*)d_ws;

    const size_t gram_off  = 0;                      // 4*8*48*48*4 = 294912 B
    const size_t asmx_off  = gram_off + 294912;      // 4*8*576*4   = 73728 B
    const size_t meff_off  = asmx_off + 73728;       // 4*36864*2   = 294912 B
    const size_t qkvwb_off = meff_off + 294912;      // 576*192*2   = 221184 B
    const size_t big_off   = (qkvwb_off + 221184 + 255) & ~(size_t)255;

    int P = 4;   // batches per pass; shrink if workspace is small
    while (P > 1 && big_off + (size_t)P * 2 * QB * 2 > ws_size) P >>= 1;

    float* gram  = (float*)(ws + gram_off);
    float* attnS = (float*)(ws + asmx_off);
    u16*   meff  = (u16*)(ws + meff_off);
    u16*   qkvwb = (u16*)(ws + qkvwb_off);
    u16*   qkvt  = (u16*)(ws + big_off);
    u16*   dwt   = qkvt + (size_t)P * QB;

    hipMemsetAsync(ws + gram_off, 0, 294912, stream);  // zero gram accumulators
    k_convert<<<dim3(108), 256, 0, stream>>>(qkvw, qkvwb, 110592 / 4);

    for (int b0 = 0; b0 < 4; b0 += P) {
        k_qkv<<<dim3(512, 3, P), 256, 0, stream>>>(qkvwb, x, qkvt, b0);
        k_dw<<<dim3(8, 256, P), 576, 0, stream>>>(qkvt, dww, dwt);
        k_gram<<<dim3(GNB, 8, P), 256, 0, stream>>>(dwt, gram, b0);
        k_softmax<<<dim3(8, P), 64, 0, stream>>>(gram, temp, attnS, b0);
        k_meff<<<dim3(P * 144), 256, 0, stream>>>(attnS, projw, meff, b0, P * 36864);
        k_gemm2<<<dim3(512, 1, P), 256, 0, stream>>>(
            meff + (size_t)b0 * 36864, dwt, out + (size_t)b0 * CD * HW);
    }
}

// Round 3
// 822.613 us; speedup vs baseline: 2.1525x; 1.1201x over previous
//
#include <hip/hip_runtime.h>
#include <stdint.h>

typedef unsigned short u16;
typedef short s16x8 __attribute__((ext_vector_type(8)));
typedef float f32x4 __attribute__((ext_vector_type(4)));

#define HW 65536
#define CD 192
#define C3 576
#define QB ((size_t)HW * C3)

static __device__ __forceinline__ float bf2f(u16 u) {
    return __uint_as_float(((uint32_t)u) << 16);
}
static __device__ __forceinline__ u16 f2bf(float f) {
    uint32_t x = __float_as_uint(f);
    return (u16)((x + 0x7fffu + ((x >> 16) & 1u)) >> 16);  // RNE
}

// ---------------------------------------------------------------------------
// convert fp32 -> bf16 (qkv_w, 576*192 elements)
// ---------------------------------------------------------------------------
__launch_bounds__(256)
__global__ void k_convert(const float* __restrict__ in, u16* __restrict__ out, int n4)
{
    int i = blockIdx.x * 256 + threadIdx.x;
    if (i >= n4) return;
    float4 v = ((const float4*)in)[i];
    ushort4 o;
    o.x = f2bf(v.x); o.y = f2bf(v.y); o.z = f2bf(v.z); o.w = f2bf(v.w);
    ((ushort4*)out)[i] = o;
}

// ---------------------------------------------------------------------------
// K1: QKV gemm (MFMA).  qkvt[p][o] = sum_c qkvw[o][c] * x[b][c][p]
// ---------------------------------------------------------------------------
__launch_bounds__(256, 2)
__global__ void k_qkv(const u16* __restrict__ A, const float* __restrict__ x,
                      u16* __restrict__ O, int b0)
{
    __shared__ __attribute__((aligned(16))) u16 As[192 * 40];
    __shared__ __attribute__((aligned(16))) u16 Xs[128 * 40];
    const int t    = threadIdx.x;
    const int pb   = blockIdx.z;
    const int m0g  = blockIdx.y * 192;
    const int p0   = blockIdx.x * 128;
    const int lane = t & 63, wid = t >> 6;
    const int quad = lane >> 4, l16 = lane & 15;
    const int wm0  = (wid >> 1) * 96, wn0 = (wid & 1) * 64;

    f32x4 acc[6][4];
    #pragma unroll
    for (int i = 0; i < 6; i++)
        #pragma unroll
        for (int j = 0; j < 4; j++) acc[i][j] = f32x4{0.f, 0.f, 0.f, 0.f};

    const float* Xb = x + (size_t)(b0 + pb) * CD * HW;

    for (int kk = 0; kk < 6; kk++) {
        if (kk) __syncthreads();
        #pragma unroll
        for (int i = 0; i < 3; i++) {           // A tile: 192x32
            int s = t + i * 256;
            int m = s >> 2, part = s & 3;
            uint4 v = *(const uint4*)(A + (size_t)(m0g + m) * CD + kk * 32 + part * 8);
            *(uint4*)(&As[m * 40 + part * 8]) = v;
        }
        #pragma unroll
        for (int i = 0; i < 4; i++) {           // X tile: 32 c x 128 p, from fp32
            int s = t + i * 256;
            int c_l = s >> 5, seg = s & 31;
            float4 v = *(const float4*)(Xb + (size_t)(kk * 32 + c_l) * HW + p0 + seg * 4);
            Xs[(seg * 4 + 0) * 40 + c_l] = f2bf(v.x);
            Xs[(seg * 4 + 1) * 40 + c_l] = f2bf(v.y);
            Xs[(seg * 4 + 2) * 40 + c_l] = f2bf(v.z);
            Xs[(seg * 4 + 3) * 40 + c_l] = f2bf(v.w);
        }
        __syncthreads();
        s16x8 af[6], bfr[4];
        #pragma unroll
        for (int i = 0; i < 6; i++)
            af[i] = *(const s16x8*)(&As[(wm0 + i * 16 + l16) * 40 + quad * 8]);
        #pragma unroll
        for (int j = 0; j < 4; j++)
            bfr[j] = *(const s16x8*)(&Xs[(wn0 + j * 16 + l16) * 40 + quad * 8]);
        #pragma unroll
        for (int i = 0; i < 6; i++)
            #pragma unroll
            for (int j = 0; j < 4; j++)
                acc[i][j] = __builtin_amdgcn_mfma_f32_16x16x32_bf16(af[i], bfr[j], acc[i][j], 0, 0, 0);
    }

    u16* Ob = O + QB * pb;
    #pragma unroll
    for (int i = 0; i < 6; i++) {
        const int o = m0g + wm0 + i * 16 + quad * 4;   // rows o..o+3
        #pragma unroll
        for (int j = 0; j < 4; j++) {
            const int p = p0 + wn0 + j * 16 + l16;
            ushort4 v;
            v.x = f2bf(acc[i][j][0]); v.y = f2bf(acc[i][j][1]);
            v.z = f2bf(acc[i][j][2]); v.w = f2bf(acc[i][j][3]);
            *(ushort4*)(Ob + (size_t)p * C3 + o) = v;
        }
    }
}

// ---------------------------------------------------------------------------
// K2 (v3): depthwise 3x3, SAME padding — persistent, no LDS, no syncthreads.
//   Thread = (cg of 4 channels, slot of 4 w-pixels). cg = cell % 144 is
//   loop-invariant (grid*block ≡ 0 mod 144) -> weights live in registers,
//   loaded once (36 contiguous fp32, 144B-aligned). 18 uint2 loads issued
//   branch-free (clamp+zero) per iteration -> deep MLP. 4-wave blocks,
//   __launch_bounds__(256,4) -> <=128 VGPR -> 16 waves/CU.
// ---------------------------------------------------------------------------
#define DW_NB 2304   // 2304*256 = 589824 = 144*4096 -> cg invariant, slot stride 4096

__launch_bounds__(256, 4)
__global__ void k_dw(const u16* __restrict__ qkv, const float* __restrict__ dww,
                     u16* __restrict__ out, int nbat)
{
    const int cell = blockIdx.x * 256 + threadIdx.x;
    const int slot0 = cell / 144;
    const int cg    = cell - slot0 * 144;      // 0..143, invariant across iters
    const int c0    = cg * 4;

    float wf[36];
    #pragma unroll
    for (int i = 0; i < 9; i++)
        *(float4*)&wf[i * 4] = *(const float4*)(dww + cg * 36 + i * 4);

    const int iters = 4 * nbat;
    for (int it = 0; it < iters; it++) {
        const int s  = slot0 + it * 4096;
        const int pb = s >> 14;                // slot / 16384
        const int p0 = (s & 16383) << 2;       // pixel base (4 consecutive w)
        const int h  = p0 >> 8;
        const int w0 = p0 & 255;

        const u16* src = qkv + (size_t)pb * QB + c0;

        // column byte-offsets + validity (shared across rows)
        int coff[6]; bool cval[6];
        #pragma unroll
        for (int c = 0; c < 6; c++) {
            int gw  = w0 + c - 1;
            cval[c] = (unsigned)gw < 256u;
            int gwc = gw < 0 ? 0 : (gw > 255 ? 255 : gw);
            coff[c] = gwc * C3;
        }

        uint2 raw[3][6];
        #pragma unroll
        for (int dh = 0; dh < 3; dh++) {
            int gh = h + dh - 1;
            bool rv = (unsigned)gh < 256u;
            int ghc = gh < 0 ? 0 : (gh > 255 ? 255 : gh);
            const u16* rs = src + (size_t)ghc * 256 * C3;
            #pragma unroll
            for (int c = 0; c < 6; c++) {
                uint2 v = *(const uint2*)(rs + coff[c]);
                bool ok = rv && cval[c];
                raw[dh][c].x = ok ? v.x : 0u;
                raw[dh][c].y = ok ? v.y : 0u;
            }
        }

        float acc[4][4];
        #pragma unroll
        for (int px = 0; px < 4; px++)
            #pragma unroll
            for (int j = 0; j < 4; j++) acc[px][j] = 0.f;

        #pragma unroll
        for (int dh = 0; dh < 3; dh++) {
            float v[6][4];
            #pragma unroll
            for (int c = 0; c < 6; c++) {
                const u16* rp = (const u16*)&raw[dh][c];
                #pragma unroll
                for (int j = 0; j < 4; j++) v[c][j] = bf2f(rp[j]);
            }
            #pragma unroll
            for (int dw = 0; dw < 3; dw++) {
                const int k = dh * 3 + dw;
                #pragma unroll
                for (int px = 0; px < 4; px++)
                    #pragma unroll
                    for (int j = 0; j < 4; j++)
                        acc[px][j] += v[px + dw][j] * wf[j * 9 + k];
            }
        }

        u16* dst = out + (size_t)pb * QB + (size_t)p0 * C3 + c0;
        #pragma unroll
        for (int px = 0; px < 4; px++) {
            uint2 o;
            o.x = (uint32_t)f2bf(acc[px][0]) | ((uint32_t)f2bf(acc[px][1]) << 16);
            o.y = (uint32_t)f2bf(acc[px][2]) | ((uint32_t)f2bf(acc[px][3]) << 16);
            *(uint2*)(dst + (size_t)px * C3) = o;
        }
    }
}

// ---------------------------------------------------------------------------
// K3: per-(b,h) 48x48 Gram matrix G = [q;k]·[q;k]^T summed over pixels (MFMA).
// ---------------------------------------------------------------------------
#define GNB    16
#define NCHUNK 16   /* (HW/GNB)/256 */

__launch_bounds__(256, 2)
__global__ void k_gram(const u16* __restrict__ dwt, float* __restrict__ gram, int b0)
{
    __shared__ __attribute__((aligned(16))) u16 S[2][48 * 264];
    const int t    = threadIdx.x;
    const int pb   = blockIdx.z, hh = blockIdx.y, blk = blockIdx.x;
    const int lane = t & 63, wid = t >> 6;
    const int quad = lane >> 4, l16 = lane & 15;
    const u16* src = dwt + (size_t)pb * QB + (size_t)blk * (HW / GNB) * C3;
    const int qcol = hh * 24, kcol = CD + hh * 24;
    const int sp_n0 = (t & 127) * 2;
    const int sp_ph = t >> 7;

    f32x4 acc[6];
    #pragma unroll
    for (int i = 0; i < 6; i++) acc[i] = f32x4{0.f, 0.f, 0.f, 0.f};

    uint4 r0[3], r1[3];

    auto stage_load = [&](int cc) {
        const u16* sp = src + (size_t)(cc * 256 + sp_n0) * C3;
        #pragma unroll
        for (int i = 0; i < 3; i++) {
            int part = i * 2 + sp_ph;
            int col  = part < 3 ? qcol + part * 8 : kcol + (part - 3) * 8;
            r0[i] = *(const uint4*)(sp + col);
            r1[i] = *(const uint4*)(sp + C3 + col);
        }
    };
    auto stage_write = [&](int bb) {
        #pragma unroll
        for (int i = 0; i < 3; i++) {
            int part = i * 2 + sp_ph;
            int dstc = part < 3 ? part * 8 : 24 + (part - 3) * 8;
            const u16* a = (const u16*)&r0[i];
            const u16* b = (const u16*)&r1[i];
            #pragma unroll
            for (int w = 0; w < 8; w++) {
                uint32_t d = (uint32_t)a[w] | ((uint32_t)b[w] << 16);
                *(uint32_t*)&S[bb][(dstc + w) * 264 + sp_n0] = d;
            }
        }
    };

    stage_load(0);
    stage_write(0);
    for (int c = 0; c < NCHUNK; c++) {
        const int bb = c & 1;
        __syncthreads();
        if (c + 1 < NCHUNK) stage_load(c + 1);
        #pragma unroll
        for (int kk = 0; kk < 2; kk++) {
            const int k0 = (wid + kk * 4) * 32 + quad * 8;
            s16x8 f0 = *(const s16x8*)&S[bb][( 0 + l16) * 264 + k0];
            s16x8 f1 = *(const s16x8*)&S[bb][(16 + l16) * 264 + k0];
            s16x8 f2 = *(const s16x8*)&S[bb][(32 + l16) * 264 + k0];
            acc[0] = __builtin_amdgcn_mfma_f32_16x16x32_bf16(f0, f0, acc[0], 0, 0, 0);
            acc[1] = __builtin_amdgcn_mfma_f32_16x16x32_bf16(f0, f1, acc[1], 0, 0, 0);
            acc[2] = __builtin_amdgcn_mfma_f32_16x16x32_bf16(f0, f2, acc[2], 0, 0, 0);
            acc[3] = __builtin_amdgcn_mfma_f32_16x16x32_bf16(f1, f1, acc[3], 0, 0, 0);
            acc[4] = __builtin_amdgcn_mfma_f32_16x16x32_bf16(f1, f2, acc[4], 0, 0, 0);
            acc[5] = __builtin_amdgcn_mfma_f32_16x16x32_bf16(f2, f2, acc[5], 0, 0, 0);
        }
        if (c + 1 < NCHUNK) stage_write(bb ^ 1);
    }

    __syncthreads();
    float* red = (float*)&S[0][0];
    #pragma unroll
    for (int tt = 0; tt < 6; tt++)
        #pragma unroll
        for (int r = 0; r < 4; r++)
            red[(wid * 6 + tt) * 256 + (quad * 4 + r) * 16 + l16] = acc[tt][r];
    __syncthreads();
    const int TIr[6] = {0, 0, 0, 1, 1, 2};
    const int TJr[6] = {0, 1, 2, 1, 2, 2};
    float* gb = gram + ((size_t)(b0 + pb) * 8 + hh) * 2304;
    #pragma unroll
    for (int k = 0; k < 6; k++) {
        float s = red[(0 * 6 + k) * 256 + t] + red[(1 * 6 + k) * 256 + t]
                + red[(2 * 6 + k) * 256 + t] + red[(3 * 6 + k) * 256 + t];
        int row = TIr[k] * 16 + (t >> 4);
        int col = TJr[k] * 16 + (t & 15);
        atomicAdd(&gb[row * 48 + col], s);
    }
}

// ---------------------------------------------------------------------------
// K4b: norm scales from Gram diag + temperature, softmax over e.
// ---------------------------------------------------------------------------
__global__ void k_softmax(const float* __restrict__ gram, const float* __restrict__ temp,
                          float* __restrict__ attnS, int b0)
{
    const int b = b0 + blockIdx.y, hh = blockIdx.x, t = threadIdx.x;
    const float* G = gram + ((size_t)b * 8 + hh) * 2304;
    __shared__ float ksc[24];
    if (t < 24) ksc[t] = 1.f / fmaxf(sqrtf(G[(24 + t) * 48 + 24 + t]), 1e-12f);
    __syncthreads();
    if (t < 24) {
        const float tp = temp[hh];
        const float qs = 1.f / fmaxf(sqrtf(G[t * 48 + t]), 1e-12f);
        const float* row = G + t * 48 + 24;
        float v[24], m = -1e30f;
        #pragma unroll
        for (int e = 0; e < 24; e++) { v[e] = row[e] * qs * ksc[e] * tp; m = fmaxf(m, v[e]); }
        float ssum = 0.f;
        #pragma unroll
        for (int e = 0; e < 24; e++) { v[e] = expf(v[e] - m); ssum += v[e]; }
        const float inv = 1.f / ssum;
        float* orow = attnS + ((size_t)b * 8 + hh) * 576 + t * 24;
        #pragma unroll
        for (int e = 0; e < 24; e++) orow[e] = v[e] * inv;
    }
}

// ---------------------------------------------------------------------------
// K4c: Meff[b][o][h*24+e] = sum_d proj_w[o][h*24+d] * attnS[b][h][d][e]
// ---------------------------------------------------------------------------
__launch_bounds__(256)
__global__ void k_meff(const float* __restrict__ attnS, const float* __restrict__ projw,
                       u16* __restrict__ meff, int b0, int total)
{
    int g = blockIdx.x * 256 + threadIdx.x;
    if (g >= total) return;
    int b_l = g / 36864, rem = g % 36864;
    int o = rem / CD, c = rem % CD;
    int hh = c / 24, e = c % 24;
    int b = b0 + b_l;
    const float* Arow = attnS + ((size_t)b * 8 + hh) * 576;
    const float* Prow = projw + o * CD + hh * 24;
    float acc = 0.f;
    #pragma unroll
    for (int d = 0; d < 24; d++) acc += Prow[d] * Arow[d * 24 + e];
    meff[(size_t)b * 36864 + o * CD + c] = f2bf(acc);
}

// ---------------------------------------------------------------------------
// K5: out[b][o][p] = sum_c meff[b][o][c] * dwt[p][384+c]   (MFMA, fp32 out)
// ---------------------------------------------------------------------------
__launch_bounds__(256, 2)
__global__ void k_gemm2(const u16* __restrict__ A, const u16* __restrict__ X,
                        float* __restrict__ O)
{
    __shared__ __attribute__((aligned(16))) u16 As[192 * 40];
    __shared__ __attribute__((aligned(16))) u16 Xs[128 * 40];
    const int t    = threadIdx.x;
    const int pb   = blockIdx.z;
    const int p0   = blockIdx.x * 128;
    const int lane = t & 63, wid = t >> 6;
    const int quad = lane >> 4, l16 = lane & 15;
    const int wm0  = (wid >> 1) * 96, wn0 = (wid & 1) * 64;

    f32x4 acc[6][4];
    #pragma unroll
    for (int i = 0; i < 6; i++)
        #pragma unroll
        for (int j = 0; j < 4; j++) acc[i][j] = f32x4{0.f, 0.f, 0.f, 0.f};

    const u16* Ab = A + (size_t)36864 * pb;
    const u16* Xb = X + QB * pb;

    for (int kk = 0; kk < 6; kk++) {
        if (kk) __syncthreads();
        #pragma unroll
        for (int i = 0; i < 3; i++) {           // A tile: 192x32
            int s = t + i * 256;
            int m = s >> 2, part = s & 3;
            uint4 v = *(const uint4*)(Ab + (size_t)m * CD + kk * 32 + part * 8);
            *(uint4*)(&As[m * 40 + part * 8]) = v;
        }
        #pragma unroll
        for (int i = 0; i < 2; i++) {           // X tile: 128 p x 32 c (v cols)
            int s = t + i * 256;
            int p = s >> 2, part = s & 3;
            uint4 v = *(const uint4*)(Xb + (size_t)(p0 + p) * C3 + 384 + kk * 32 + part * 8);
            *(uint4*)(&Xs[p * 40 + part * 8]) = v;
        }
        __syncthreads();
        s16x8 af[6], bfr[4];
        #pragma unroll
        for (int i = 0; i < 6; i++)
            af[i] = *(const s16x8*)(&As[(wm0 + i * 16 + l16) * 40 + quad * 8]);
        #pragma unroll
        for (int j = 0; j < 4; j++)
            bfr[j] = *(const s16x8*)(&Xs[(wn0 + j * 16 + l16) * 40 + quad * 8]);
        #pragma unroll
        for (int i = 0; i < 6; i++)
            #pragma unroll
            for (int j = 0; j < 4; j++)
                acc[i][j] = __builtin_amdgcn_mfma_f32_16x16x32_bf16(af[i], bfr[j], acc[i][j], 0, 0, 0);
    }

    float* Ob = O + (size_t)CD * HW * pb;
    #pragma unroll
    for (int i = 0; i < 6; i++) {
        const int o = wm0 + i * 16 + quad * 4;
        #pragma unroll
        for (int j = 0; j < 4; j++) {
            const int p = p0 + wn0 + j * 16 + l16;
            #pragma unroll
            for (int r = 0; r < 4; r++)
                Ob[(size_t)(o + r) * HW + p] = acc[i][j][r];
        }
    }
}

// ---------------------------------------------------------------------------
extern "C" void kernel_launch(void* const* d_in, const int* in_sizes, int n_in,
                              void* d_out, int out_size, void* d_ws, size_t ws_size,
                              hipStream_t stream)
{
    (void)out_size;
    const float* x     = (const float*)d_in[0];
    const float* qkvw  = (const float*)d_in[1];
    const float* dww   = (const float*)d_in[2];
    const float* projw = (const float*)d_in[3];
    const float* temp  = (const float*)d_in[4];
    for (int i = 0; i < n_in; i++) {
        switch (in_sizes[i]) {
            case 50331648: x     = (const float*)d_in[i]; break;
            case 110592:   qkvw  = (const float*)d_in[i]; break;
            case 5184:     dww   = (const float*)d_in[i]; break;
            case 36864:    projw = (const float*)d_in[i]; break;
            case 8:        temp  = (const float*)d_in[i]; break;
            default: break;
        }
    }
    float* out = (float*)d_out;          // reference output dtype = float32
    char* ws = (char*)d_ws;

    const size_t gram_off  = 0;                      // 4*8*48*48*4 = 294912 B
    const size_t asmx_off  = gram_off + 294912;      // 4*8*576*4   = 73728 B
    const size_t meff_off  = asmx_off + 73728;       // 4*36864*2   = 294912 B
    const size_t qkvwb_off = meff_off + 294912;      // 576*192*2   = 221184 B
    const size_t big_off   = (qkvwb_off + 221184 + 255) & ~(size_t)255;

    int P = 4;   // batches per pass; shrink if workspace is small
    while (P > 1 && big_off + (size_t)P * 2 * QB * 2 > ws_size) P >>= 1;

    float* gram  = (float*)(ws + gram_off);
    float* attnS = (float*)(ws + asmx_off);
    u16*   meff  = (u16*)(ws + meff_off);
    u16*   qkvwb = (u16*)(ws + qkvwb_off);
    u16*   qkvt  = (u16*)(ws + big_off);
    u16*   dwt   = qkvt + (size_t)P * QB;

    hipMemsetAsync(ws + gram_off, 0, 294912, stream);  // zero gram accumulators
    k_convert<<<dim3(108), 256, 0, stream>>>(qkvw, qkvwb, 110592 / 4);

    for (int b0 = 0; b0 < 4; b0 += P) {
        k_qkv<<<dim3(512, 3, P), 256, 0, stream>>>(qkvwb, x, qkvt, b0);
        k_dw<<<dim3(DW_NB), 256, 0, stream>>>(qkvt, dww, dwt, P);
        k_gram<<<dim3(GNB, 8, P), 256, 0, stream>>>(dwt, gram, b0);
        k_softmax<<<dim3(8, P), 64, 0, stream>>>(gram, temp, attnS, b0);
        k_meff<<<dim3(P * 144), 256, 0, stream>>>(attnS, projw, meff, b0, P * 36864);
        k_gemm2<<<dim3(512, 1, P), 256, 0, stream>>>(
            meff + (size_t)b0 * 36864, dwt, out + (size_t)b0 * CD * HW);
    }
}